// Round 1
// baseline (114.428 us; speedup 1.0000x reference)
//
#include <hip/hip_runtime.h>
#include <hip/hip_bf16.h>

#define NTOK 2048
#define DDIM 512
#define NBATCH 8

using bf16x8 = __attribute__((ext_vector_type(8))) short;
using f32x4  = __attribute__((ext_vector_type(4))) float;

__device__ __forceinline__ short f2bf(float f) {
  __hip_bfloat16 h = __float2bfloat16(f);
  union { __hip_bfloat16 h; short s; } u; u.h = h;
  return u.s;
}

// S[b][i][j] = sum_d X[b][i][d] * X[b][j][d], bf16 MFMA, fp32 accumulate.
// 128x128 tile per block, BK=64, 4 waves each computing a 64x64 quadrant
// as 4x4 fragments of mfma_f32_16x16x32_bf16.
__global__ __launch_bounds__(256) void scores_kernel(const float* __restrict__ X,
                                                     float* __restrict__ S) {
  const int b  = blockIdx.z;
  const int i0 = blockIdx.y * 128;
  const int j0 = blockIdx.x * 128;
  const float* Xb = X + (size_t)b * NTOK * DDIM;
  float* Sb = S + (size_t)b * NTOK * NTOK;

  __shared__ short lds_a[128][64];
  __shared__ short lds_b[128][64];

  const int t    = threadIdx.x;
  const int lane = t & 63;
  const int w    = t >> 6;
  const int wr   = (w >> 1) * 64;   // wave row offset in tile
  const int wc   = (w & 1) * 64;    // wave col offset in tile
  const int lr   = lane & 15;       // fragment row/col
  const int lk   = (lane >> 4) * 8; // fragment k base (8 contiguous bf16)

  f32x4 acc[4][4] = {};

  for (int k0 = 0; k0 < DDIM; k0 += 64) {
    // ---- stage: 128x64 fp32 -> bf16 into LDS (A from i0 rows, B from j0 rows)
#pragma unroll
    for (int q = 0; q < 8; ++q) {
      const int v  = t + 256 * q;      // float4 index in [0, 2048)
      const int r  = v >> 4;           // row 0..127
      const int c4 = (v & 15) * 4;     // col (floats) 0..60
      const float4 va = *reinterpret_cast<const float4*>(
          Xb + (size_t)(i0 + r) * DDIM + k0 + c4);
      const float4 vb = *reinterpret_cast<const float4*>(
          Xb + (size_t)(j0 + r) * DDIM + k0 + c4);
      short4 sa, sb;
      sa.x = f2bf(va.x); sa.y = f2bf(va.y); sa.z = f2bf(va.z); sa.w = f2bf(va.w);
      sb.x = f2bf(vb.x); sb.y = f2bf(vb.y); sb.z = f2bf(vb.z); sb.w = f2bf(vb.w);
      *reinterpret_cast<short4*>(&lds_a[r][c4]) = sa;
      *reinterpret_cast<short4*>(&lds_b[r][c4]) = sb;
    }
    __syncthreads();

    // ---- compute: 2 k-subtiles of 32, 16 MFMA each
#pragma unroll
    for (int ks = 0; ks < 2; ++ks) {
      bf16x8 af[4], bfr[4];
#pragma unroll
      for (int m = 0; m < 4; ++m)
        af[m] = *reinterpret_cast<const bf16x8*>(&lds_a[wr + m * 16 + lr][ks * 32 + lk]);
#pragma unroll
      for (int n = 0; n < 4; ++n)
        bfr[n] = *reinterpret_cast<const bf16x8*>(&lds_b[wc + n * 16 + lr][ks * 32 + lk]);
#pragma unroll
      for (int m = 0; m < 4; ++m)
#pragma unroll
        for (int n = 0; n < 4; ++n)
          acc[m][n] = __builtin_amdgcn_mfma_f32_16x16x32_bf16(af[m], bfr[n], acc[m][n], 0, 0, 0);
    }
    __syncthreads();
  }

  // ---- epilogue: C/D layout col = lane&15, row = (lane>>4)*4 + reg  [m89/m91]
  const int crow = (lane >> 4) * 4;
  const int ccol = lane & 15;
#pragma unroll
  for (int m = 0; m < 4; ++m) {
#pragma unroll
    for (int n = 0; n < 4; ++n) {
      const int gr = i0 + wr + m * 16 + crow;
      const int gc = j0 + wc + n * 16 + ccol;
      float* outp = Sb + (size_t)gr * NTOK + gc;
#pragma unroll
      for (int r = 0; r < 4; ++r)
        outp[(size_t)r * NTOK] = acc[m][n][r];
    }
  }
}

// In-place row softmax: one 256-thread block per row of 2048 fp32.
__global__ __launch_bounds__(256) void softmax_kernel(float* __restrict__ S) {
  float* row = S + (size_t)blockIdx.x * NTOK;
  const int t    = threadIdx.x;
  const int lane = t & 63;
  const int w    = t >> 6;

  float4* rv = reinterpret_cast<float4*>(row);
  float4 a = rv[t];
  float4 b = rv[t + 256];

  float m = fmaxf(fmaxf(fmaxf(a.x, a.y), fmaxf(a.z, a.w)),
                  fmaxf(fmaxf(b.x, b.y), fmaxf(b.z, b.w)));
#pragma unroll
  for (int off = 32; off > 0; off >>= 1) m = fmaxf(m, __shfl_xor(m, off));

  __shared__ float redm[4];
  __shared__ float reds[4];
  if (lane == 0) redm[w] = m;
  __syncthreads();
  m = fmaxf(fmaxf(redm[0], redm[1]), fmaxf(redm[2], redm[3]));

  a.x = __expf(a.x - m); a.y = __expf(a.y - m);
  a.z = __expf(a.z - m); a.w = __expf(a.w - m);
  b.x = __expf(b.x - m); b.y = __expf(b.y - m);
  b.z = __expf(b.z - m); b.w = __expf(b.w - m);

  float s = (a.x + a.y + a.z + a.w) + (b.x + b.y + b.z + b.w);
#pragma unroll
  for (int off = 32; off > 0; off >>= 1) s += __shfl_xor(s, off);
  if (lane == 0) reds[w] = s;
  __syncthreads();
  s = reds[0] + reds[1] + reds[2] + reds[3];

  const float inv = 1.0f / s;
  a.x *= inv; a.y *= inv; a.z *= inv; a.w *= inv;
  b.x *= inv; b.y *= inv; b.z *= inv; b.w *= inv;
  rv[t] = a;
  rv[t + 256] = b;
}

extern "C" void kernel_launch(void* const* d_in, const int* in_sizes, int n_in,
                              void* d_out, int out_size, void* d_ws, size_t ws_size,
                              hipStream_t stream) {
  const float* X = (const float*)d_in[0];
  float* out = (float*)d_out;

  dim3 ggrid(NTOK / 128, NTOK / 128, NBATCH);  // 16 x 16 x 8
  scores_kernel<<<ggrid, 256, 0, stream>>>(X, out);
  softmax_kernel<<<NBATCH * NTOK, 256, 0, stream>>>(out);
}

// Round 2
// 106.711 us; speedup vs baseline: 1.0723x; 1.0723x over previous
//
#include <hip/hip_runtime.h>
#include <hip/hip_bf16.h>

#define NTOK 2048
#define DDIM 512
#define NBATCH 8

using bf16x8 = __attribute__((ext_vector_type(8))) short;
using f32x4  = __attribute__((ext_vector_type(4))) float;

__device__ __forceinline__ short f2bf(float f) {
  __hip_bfloat16 h = __float2bfloat16(f);
  union { __hip_bfloat16 h; short s; } u; u.h = h;
  return u.s;
}

__device__ __forceinline__ void async_copy16(void* lds, const void* g) {
  __builtin_amdgcn_global_load_lds(
      (const __attribute__((address_space(1))) void*)g,
      (__attribute__((address_space(3))) void*)lds,
      16, 0, 0);
}

// fp32 -> bf16 pre-convert: each thread handles 8 floats -> one 16B bf16x8 store.
__global__ __launch_bounds__(256) void convert_kernel(const float* __restrict__ X,
                                                      short* __restrict__ Y) {
  const int i = blockIdx.x * 256 + threadIdx.x;  // 8 elements per thread
  const float4* xv = reinterpret_cast<const float4*>(X);
  const float4 a = xv[(size_t)i * 2];
  const float4 b = xv[(size_t)i * 2 + 1];
  bf16x8 o;
  o[0] = f2bf(a.x); o[1] = f2bf(a.y); o[2] = f2bf(a.z); o[3] = f2bf(a.w);
  o[4] = f2bf(b.x); o[5] = f2bf(b.y); o[6] = f2bf(b.z); o[7] = f2bf(b.w);
  *reinterpret_cast<bf16x8*>(Y + (size_t)i * 8) = o;
}

// m97-structure scores kernel: bf16 input, global_load_lds width-16 staging,
// 128x128 tile, BK=64, 4 waves x (64x64 as 4x4 mfma_f32_16x16x32_bf16).
__global__ __launch_bounds__(256) void scores_bf16_kernel(const short* __restrict__ X16,
                                                          float* __restrict__ S) {
  const int b  = blockIdx.z;
  const int i0 = blockIdx.y * 128;
  const int j0 = blockIdx.x * 128;
  const short* Xb = X16 + (size_t)b * NTOK * DDIM;
  float* Sb = S + (size_t)b * NTOK * NTOK;

  __shared__ short lds_a[128 * 64];   // linear [row][col], 16 KB
  __shared__ short lds_b[128 * 64];

  const int t    = threadIdx.x;
  const int lane = t & 63;
  const int w    = t >> 6;
  const int wr   = (w >> 1) * 64;
  const int wc   = (w & 1) * 64;
  const int lr   = lane & 15;
  const int lk   = (lane >> 4) * 8;

  // staging geometry: per call, wave stages 64 lanes x 16B = 1024B = 8 rows
  const int srow = lane >> 3;          // row within 8-row segment
  const int scb  = (lane & 7) * 16;    // byte col within 128-B row

  f32x4 acc[4][4] = {};

  for (int k0 = 0; k0 < DDIM; k0 += 64) {
#pragma unroll
    for (int q = 0; q < 4; ++q) {
      const int seg = q * 4 + w;            // 0..15 (wave-uniform)
      const int row = seg * 8 + srow;       // 0..127 (per-lane)
      const char* gA = (const char*)(Xb + (size_t)(i0 + row) * DDIM + k0) + scb;
      const char* gB = (const char*)(Xb + (size_t)(j0 + row) * DDIM + k0) + scb;
      async_copy16(&lds_a[seg * 512], gA);
      async_copy16(&lds_b[seg * 512], gB);
    }
    __syncthreads();

#pragma unroll
    for (int ks = 0; ks < 2; ++ks) {
      bf16x8 af[4], bfr[4];
#pragma unroll
      for (int m = 0; m < 4; ++m)
        af[m] = *reinterpret_cast<const bf16x8*>(&lds_a[(wr + m * 16 + lr) * 64 + ks * 32 + lk]);
#pragma unroll
      for (int n = 0; n < 4; ++n)
        bfr[n] = *reinterpret_cast<const bf16x8*>(&lds_b[(wc + n * 16 + lr) * 64 + ks * 32 + lk]);
#pragma unroll
      for (int m = 0; m < 4; ++m)
#pragma unroll
        for (int n = 0; n < 4; ++n)
          acc[m][n] = __builtin_amdgcn_mfma_f32_16x16x32_bf16(af[m], bfr[n], acc[m][n], 0, 0, 0);
    }
    __syncthreads();
  }

  const int crow = (lane >> 4) * 4;
  const int ccol = lane & 15;
#pragma unroll
  for (int m = 0; m < 4; ++m) {
#pragma unroll
    for (int n = 0; n < 4; ++n) {
      const int gr = i0 + wr + m * 16 + crow;
      const int gc = j0 + wc + n * 16 + ccol;
      float* outp = Sb + (size_t)gr * NTOK + gc;
#pragma unroll
      for (int r = 0; r < 4; ++r)
        outp[(size_t)r * NTOK] = acc[m][n][r];
    }
  }
}

// Fallback (round-1 verified): fp32 input, convert during staging.
__global__ __launch_bounds__(256) void scores_kernel(const float* __restrict__ X,
                                                     float* __restrict__ S) {
  const int b  = blockIdx.z;
  const int i0 = blockIdx.y * 128;
  const int j0 = blockIdx.x * 128;
  const float* Xb = X + (size_t)b * NTOK * DDIM;
  float* Sb = S + (size_t)b * NTOK * NTOK;

  __shared__ short lds_a[128][64];
  __shared__ short lds_b[128][64];

  const int t    = threadIdx.x;
  const int lane = t & 63;
  const int w    = t >> 6;
  const int wr   = (w >> 1) * 64;
  const int wc   = (w & 1) * 64;
  const int lr   = lane & 15;
  const int lk   = (lane >> 4) * 8;

  f32x4 acc[4][4] = {};

  for (int k0 = 0; k0 < DDIM; k0 += 64) {
#pragma unroll
    for (int q = 0; q < 8; ++q) {
      const int v  = t + 256 * q;
      const int r  = v >> 4;
      const int c4 = (v & 15) * 4;
      const float4 va = *reinterpret_cast<const float4*>(
          Xb + (size_t)(i0 + r) * DDIM + k0 + c4);
      const float4 vb = *reinterpret_cast<const float4*>(
          Xb + (size_t)(j0 + r) * DDIM + k0 + c4);
      short4 sa, sb;
      sa.x = f2bf(va.x); sa.y = f2bf(va.y); sa.z = f2bf(va.z); sa.w = f2bf(va.w);
      sb.x = f2bf(vb.x); sb.y = f2bf(vb.y); sb.z = f2bf(vb.z); sb.w = f2bf(vb.w);
      *reinterpret_cast<short4*>(&lds_a[r][c4]) = sa;
      *reinterpret_cast<short4*>(&lds_b[r][c4]) = sb;
    }
    __syncthreads();

#pragma unroll
    for (int ks = 0; ks < 2; ++ks) {
      bf16x8 af[4], bfr[4];
#pragma unroll
      for (int m = 0; m < 4; ++m)
        af[m] = *reinterpret_cast<const bf16x8*>(&lds_a[wr + m * 16 + lr][ks * 32 + lk]);
#pragma unroll
      for (int n = 0; n < 4; ++n)
        bfr[n] = *reinterpret_cast<const bf16x8*>(&lds_b[wc + n * 16 + lr][ks * 32 + lk]);
#pragma unroll
      for (int m = 0; m < 4; ++m)
#pragma unroll
        for (int n = 0; n < 4; ++n)
          acc[m][n] = __builtin_amdgcn_mfma_f32_16x16x32_bf16(af[m], bfr[n], acc[m][n], 0, 0, 0);
    }
    __syncthreads();
  }

  const int crow = (lane >> 4) * 4;
  const int ccol = lane & 15;
#pragma unroll
  for (int m = 0; m < 4; ++m) {
#pragma unroll
    for (int n = 0; n < 4; ++n) {
      const int gr = i0 + wr + m * 16 + crow;
      const int gc = j0 + wc + n * 16 + ccol;
      float* outp = Sb + (size_t)gr * NTOK + gc;
#pragma unroll
      for (int r = 0; r < 4; ++r)
        outp[(size_t)r * NTOK] = acc[m][n][r];
    }
  }
}

// In-place row softmax: one 256-thread block per row of 2048 fp32.
__global__ __launch_bounds__(256) void softmax_kernel(float* __restrict__ S) {
  float* row = S + (size_t)blockIdx.x * NTOK;
  const int t    = threadIdx.x;
  const int lane = t & 63;
  const int w    = t >> 6;

  float4* rv = reinterpret_cast<float4*>(row);
  float4 a = rv[t];
  float4 b = rv[t + 256];

  float m = fmaxf(fmaxf(fmaxf(a.x, a.y), fmaxf(a.z, a.w)),
                  fmaxf(fmaxf(b.x, b.y), fmaxf(b.z, b.w)));
#pragma unroll
  for (int off = 32; off > 0; off >>= 1) m = fmaxf(m, __shfl_xor(m, off));

  __shared__ float redm[4];
  __shared__ float reds[4];
  if (lane == 0) redm[w] = m;
  __syncthreads();
  m = fmaxf(fmaxf(redm[0], redm[1]), fmaxf(redm[2], redm[3]));

  a.x = __expf(a.x - m); a.y = __expf(a.y - m);
  a.z = __expf(a.z - m); a.w = __expf(a.w - m);
  b.x = __expf(b.x - m); b.y = __expf(b.y - m);
  b.z = __expf(b.z - m); b.w = __expf(b.w - m);

  float s = (a.x + a.y + a.z + a.w) + (b.x + b.y + b.z + b.w);
#pragma unroll
  for (int off = 32; off > 0; off >>= 1) s += __shfl_xor(s, off);
  if (lane == 0) reds[w] = s;
  __syncthreads();
  s = reds[0] + reds[1] + reds[2] + reds[3];

  const float inv = 1.0f / s;
  a.x *= inv; a.y *= inv; a.z *= inv; a.w *= inv;
  b.x *= inv; b.y *= inv; b.z *= inv; b.w *= inv;
  rv[t] = a;
  rv[t + 256] = b;
}

extern "C" void kernel_launch(void* const* d_in, const int* in_sizes, int n_in,
                              void* d_out, int out_size, void* d_ws, size_t ws_size,
                              hipStream_t stream) {
  const float* X = (const float*)d_in[0];
  float* out = (float*)d_out;

  const size_t need = (size_t)NBATCH * NTOK * DDIM * sizeof(short);  // 16.8 MB
  dim3 ggrid(NTOK / 128, NTOK / 128, NBATCH);  // 16 x 16 x 8

  if (ws_size >= need) {
    short* Xb16 = (short*)d_ws;
    const int n_threads = NBATCH * NTOK * DDIM / 8;  // 8 floats per thread
    convert_kernel<<<n_threads / 256, 256, 0, stream>>>(X, Xb16);
    scores_bf16_kernel<<<ggrid, 256, 0, stream>>>(Xb16, out);
  } else {
    scores_kernel<<<ggrid, 256, 0, stream>>>(X, out);
  }
  softmax_kernel<<<NBATCH * NTOK, 256, 0, stream>>>(out);
}

// Round 3
// 97.400 us; speedup vs baseline: 1.1748x; 1.0956x over previous
//
#include <hip/hip_runtime.h>
#include <hip/hip_bf16.h>

#define NTOK 2048
#define DDIM 512
#define NBATCH 8

using bf16x8 = __attribute__((ext_vector_type(8))) short;
using f32x4  = __attribute__((ext_vector_type(4))) float;

__device__ __forceinline__ short f2bf(float f) {
  __hip_bfloat16 h = __float2bfloat16(f);
  union { __hip_bfloat16 h; short s; } u; u.h = h;
  return u.s;
}

__device__ __forceinline__ void async_copy16(void* lds, const void* g) {
  __builtin_amdgcn_global_load_lds(
      (const __attribute__((address_space(1))) void*)g,
      (__attribute__((address_space(3))) void*)lds,
      16, 0, 0);
}

// fp32 -> bf16 pre-convert: each thread handles 8 floats -> one 16B bf16x8 store.
__global__ __launch_bounds__(256) void convert_kernel(const float* __restrict__ X,
                                                      short* __restrict__ Y) {
  const int i = blockIdx.x * 256 + threadIdx.x;
  const float4* xv = reinterpret_cast<const float4*>(X);
  const float4 a = xv[(size_t)i * 2];
  const float4 b = xv[(size_t)i * 2 + 1];
  bf16x8 o;
  o[0] = f2bf(a.x); o[1] = f2bf(a.y); o[2] = f2bf(a.z); o[3] = f2bf(a.w);
  o[4] = f2bf(b.x); o[5] = f2bf(b.y); o[6] = f2bf(b.z); o[7] = f2bf(b.w);
  *reinterpret_cast<bf16x8*>(Y + (size_t)i * 8) = o;
}

// Symmetric scores kernel: only upper-triangle block pairs (bi <= bj).
// m97 structure: bf16 input, global_load_lds width-16 staging, 128x128 tile,
// BK=64, 4 waves x (64x64 as 4x4 mfma_f32_16x16x32_bf16).
// Off-diagonal blocks also write the mirrored tile with float4 stores.
__global__ __launch_bounds__(256) void scores_sym_kernel(const short* __restrict__ X16,
                                                         float* __restrict__ S) {
  // triangular index: blockIdx.x in [0, 136) -> (bi, bj), bi <= bj
  int rem = blockIdx.x;
  int bi = 0;
  while (rem >= 16 - bi) { rem -= 16 - bi; ++bi; }
  const int bj = bi + rem;

  const int b  = blockIdx.z;
  const int i0 = bi * 128;
  const int j0 = bj * 128;
  const short* Xb = X16 + (size_t)b * NTOK * DDIM;
  float* Sb = S + (size_t)b * NTOK * NTOK;

  __shared__ short lds_a[128 * 64];   // linear [row][col-within-BK], 16 KB
  __shared__ short lds_b[128 * 64];

  const int t    = threadIdx.x;
  const int lane = t & 63;
  const int w    = t >> 6;
  const int wr   = (w >> 1) * 64;
  const int wc   = (w & 1) * 64;
  const int lr   = lane & 15;
  const int lk   = (lane >> 4) * 8;

  const int srow = lane >> 3;          // row within 8-row segment
  const int scb  = (lane & 7) * 16;    // byte col within 128-B row

  f32x4 acc[4][4] = {};

  for (int k0 = 0; k0 < DDIM; k0 += 64) {
#pragma unroll
    for (int q = 0; q < 4; ++q) {
      const int seg = q * 4 + w;            // wave-uniform
      const int row = seg * 8 + srow;       // per-lane
      const char* gA = (const char*)(Xb + (size_t)(i0 + row) * DDIM + k0) + scb;
      const char* gB = (const char*)(Xb + (size_t)(j0 + row) * DDIM + k0) + scb;
      async_copy16(&lds_a[seg * 512], gA);
      async_copy16(&lds_b[seg * 512], gB);
    }
    __syncthreads();

#pragma unroll
    for (int ks = 0; ks < 2; ++ks) {
      bf16x8 af[4], bfr[4];
#pragma unroll
      for (int m = 0; m < 4; ++m)
        af[m] = *reinterpret_cast<const bf16x8*>(&lds_a[(wr + m * 16 + lr) * 64 + ks * 32 + lk]);
#pragma unroll
      for (int n = 0; n < 4; ++n)
        bfr[n] = *reinterpret_cast<const bf16x8*>(&lds_b[(wc + n * 16 + lr) * 64 + ks * 32 + lk]);
#pragma unroll
      for (int m = 0; m < 4; ++m)
#pragma unroll
        for (int n = 0; n < 4; ++n)
          acc[m][n] = __builtin_amdgcn_mfma_f32_16x16x32_bf16(af[m], bfr[n], acc[m][n], 0, 0, 0);
    }
    __syncthreads();
  }

  // C/D layout: col = lane&15, row = (lane>>4)*4 + reg  [m89/m91]
  const int crow = (lane >> 4) * 4;
  const int ccol = lane & 15;

  // normal tile (always)
#pragma unroll
  for (int m = 0; m < 4; ++m) {
#pragma unroll
    for (int n = 0; n < 4; ++n) {
      const int gr = i0 + wr + m * 16 + crow;
      const int gc = j0 + wc + n * 16 + ccol;
      float* outp = Sb + (size_t)gr * NTOK + gc;
#pragma unroll
      for (int r = 0; r < 4; ++r)
        outp[(size_t)r * NTOK] = acc[m][n][r];
    }
  }

  // mirrored tile (off-diagonal only): acc[m][n][0..3] = rows gr..gr+3 at col gc
  // -> transposed it's 4 consecutive cols at row gc = one aligned float4.
  if (bi != bj) {
#pragma unroll
    for (int m = 0; m < 4; ++m) {
#pragma unroll
      for (int n = 0; n < 4; ++n) {
        const int gr = i0 + wr + m * 16 + crow;   // multiple of 4 -> 16B aligned
        const int gc = j0 + wc + n * 16 + ccol;
        *reinterpret_cast<f32x4*>(Sb + (size_t)gc * NTOK + gr) = acc[m][n];
      }
    }
  }
}

// Fallback (round-1 verified): fp32 input, convert during staging, full grid.
__global__ __launch_bounds__(256) void scores_kernel(const float* __restrict__ X,
                                                     float* __restrict__ S) {
  const int b  = blockIdx.z;
  const int i0 = blockIdx.y * 128;
  const int j0 = blockIdx.x * 128;
  const float* Xb = X + (size_t)b * NTOK * DDIM;
  float* Sb = S + (size_t)b * NTOK * NTOK;

  __shared__ short lds_a[128][64];
  __shared__ short lds_b[128][64];

  const int t    = threadIdx.x;
  const int lane = t & 63;
  const int w    = t >> 6;
  const int wr   = (w >> 1) * 64;
  const int wc   = (w & 1) * 64;
  const int lr   = lane & 15;
  const int lk   = (lane >> 4) * 8;

  f32x4 acc[4][4] = {};

  for (int k0 = 0; k0 < DDIM; k0 += 64) {
#pragma unroll
    for (int q = 0; q < 8; ++q) {
      const int v  = t + 256 * q;
      const int r  = v >> 4;
      const int c4 = (v & 15) * 4;
      const float4 va = *reinterpret_cast<const float4*>(
          Xb + (size_t)(i0 + r) * DDIM + k0 + c4);
      const float4 vb = *reinterpret_cast<const float4*>(
          Xb + (size_t)(j0 + r) * DDIM + k0 + c4);
      short4 sa, sb;
      sa.x = f2bf(va.x); sa.y = f2bf(va.y); sa.z = f2bf(va.z); sa.w = f2bf(va.w);
      sb.x = f2bf(vb.x); sb.y = f2bf(vb.y); sb.z = f2bf(vb.z); sb.w = f2bf(vb.w);
      *reinterpret_cast<short4*>(&lds_a[r][c4]) = sa;
      *reinterpret_cast<short4*>(&lds_b[r][c4]) = sb;
    }
    __syncthreads();

#pragma unroll
    for (int ks = 0; ks < 2; ++ks) {
      bf16x8 af[4], bfr[4];
#pragma unroll
      for (int m = 0; m < 4; ++m)
        af[m] = *reinterpret_cast<const bf16x8*>(&lds_a[wr + m * 16 + lr][ks * 32 + lk]);
#pragma unroll
      for (int n = 0; n < 4; ++n)
        bfr[n] = *reinterpret_cast<const bf16x8*>(&lds_b[wc + n * 16 + lr][ks * 32 + lk]);
#pragma unroll
      for (int m = 0; m < 4; ++m)
#pragma unroll
        for (int n = 0; n < 4; ++n)
          acc[m][n] = __builtin_amdgcn_mfma_f32_16x16x32_bf16(af[m], bfr[n], acc[m][n], 0, 0, 0);
    }
    __syncthreads();
  }

  const int crow = (lane >> 4) * 4;
  const int ccol = lane & 15;
#pragma unroll
  for (int m = 0; m < 4; ++m) {
#pragma unroll
    for (int n = 0; n < 4; ++n) {
      const int gr = i0 + wr + m * 16 + crow;
      const int gc = j0 + wc + n * 16 + ccol;
      float* outp = Sb + (size_t)gr * NTOK + gc;
#pragma unroll
      for (int r = 0; r < 4; ++r)
        outp[(size_t)r * NTOK] = acc[m][n][r];
    }
  }
}

// In-place row softmax: one 256-thread block per row of 2048 fp32.
__global__ __launch_bounds__(256) void softmax_kernel(float* __restrict__ S) {
  float* row = S + (size_t)blockIdx.x * NTOK;
  const int t    = threadIdx.x;
  const int lane = t & 63;
  const int w    = t >> 6;

  float4* rv = reinterpret_cast<float4*>(row);
  float4 a = rv[t];
  float4 b = rv[t + 256];

  float m = fmaxf(fmaxf(fmaxf(a.x, a.y), fmaxf(a.z, a.w)),
                  fmaxf(fmaxf(b.x, b.y), fmaxf(b.z, b.w)));
#pragma unroll
  for (int off = 32; off > 0; off >>= 1) m = fmaxf(m, __shfl_xor(m, off));

  __shared__ float redm[4];
  __shared__ float reds[4];
  if (lane == 0) redm[w] = m;
  __syncthreads();
  m = fmaxf(fmaxf(redm[0], redm[1]), fmaxf(redm[2], redm[3]));

  a.x = __expf(a.x - m); a.y = __expf(a.y - m);
  a.z = __expf(a.z - m); a.w = __expf(a.w - m);
  b.x = __expf(b.x - m); b.y = __expf(b.y - m);
  b.z = __expf(b.z - m); b.w = __expf(b.w - m);

  float s = (a.x + a.y + a.z + a.w) + (b.x + b.y + b.z + b.w);
#pragma unroll
  for (int off = 32; off > 0; off >>= 1) s += __shfl_xor(s, off);
  if (lane == 0) reds[w] = s;
  __syncthreads();
  s = reds[0] + reds[1] + reds[2] + reds[3];

  const float inv = 1.0f / s;
  a.x *= inv; a.y *= inv; a.z *= inv; a.w *= inv;
  b.x *= inv; b.y *= inv; b.z *= inv; b.w *= inv;
  rv[t] = a;
  rv[t + 256] = b;
}

extern "C" void kernel_launch(void* const* d_in, const int* in_sizes, int n_in,
                              void* d_out, int out_size, void* d_ws, size_t ws_size,
                              hipStream_t stream) {
  const float* X = (const float*)d_in[0];
  float* out = (float*)d_out;

  const size_t need = (size_t)NBATCH * NTOK * DDIM * sizeof(short);  // 16.8 MB

  if (ws_size >= need) {
    short* Xb16 = (short*)d_ws;
    const int n_threads = NBATCH * NTOK * DDIM / 8;
    convert_kernel<<<n_threads / 256, 256, 0, stream>>>(X, Xb16);
    dim3 sgrid(136, 1, NBATCH);  // 16*17/2 upper-triangle block pairs per batch
    scores_sym_kernel<<<sgrid, 256, 0, stream>>>(Xb16, out);
  } else {
    dim3 ggrid(NTOK / 128, NTOK / 128, NBATCH);
    scores_kernel<<<ggrid, 256, 0, stream>>>(X, out);
  }
  softmax_kernel<<<NBATCH * NTOK, 256, 0, stream>>>(out);
}